// Round 4
// baseline (320.647 us; speedup 1.0000x reference)
//
#include <hip/hip_runtime.h>

#define BINS 30
#define MMT 0.75f
#define LOSS_WEIGHT 1.0f

#define RSTRIDE 31            // 30 bins + 1 pad; row r bin b -> bank (b-r)%32
#define NTHREADS 256
#define NROWS (NTHREADS / 2)  // 2 threads share a row via ds_add (no-return atomic)
#define HWORDS (NROWS * RSTRIDE)      // 3968 words = 15872 B
#define CNT_ONE (1u << 20)    // count in bits [20..31]; fixed-point sum in bits [0..19]
#define SUM_MASK 0xFFFFFu
#define SSCALE 256.0f
#define INV_SSCALE (1.0f / 256.0f)

typedef __attribute__((ext_vector_type(4))) float f32x4;
typedef __attribute__((ext_vector_type(4))) int   i32x4;

// Workspace: float gS[64] @0, uint gC[64] @256, uint gDone @512 (zeroed each launch)

__device__ __forceinline__ void ghm_elem(float x, int tt, unsigned int* __restrict__ row) {
    // g = |sigmoid(x)-t| = sigmoid(z), bce = softplus(z), z=(1-2t)x
    float z = tt ? -x : x;
    float a = __expf(-fabsf(z));               // e^{-|z|} in (0,1]
    float h = 1.0f + a;
    float r = __builtin_amdgcn_rcpf(h);        // sigmoid(|z|)
    float g = (z >= 0.0f) ? r : 1.0f - r;      // sigmoid(z)
    float sp = fmaxf(z, 0.0f) + __logf(h);     // softplus(z) >= 0
    int b = (int)(g * 30.0f);
    b = b > (BINS - 1) ? (BINS - 1) : b;
    b = b < 0 ? 0 : b;
    // fused count|fixedpoint-sum; fire-and-forget LDS atomic (ds_add, no return)
    atomicAdd(&row[b], (unsigned int)(sp * SSCALE + 0.5f) + CNT_ONE);
}

// Volatile asm loads: the compiler sank every source-level prefetch (r1: VGPR=24,
// r3: VGPR=32 -> pipeline DCE'd into vmcnt(0)-per-group, 2.4 TB/s MLP-starved floor).
// asm cannot be sunk; 32B of pred + 32B of tgt per group in one clause pair.
__device__ __forceinline__ void issue4(unsigned long long pa, unsigned long long ta,
                                       f32x4& P0, f32x4& P1, i32x4& Q0, i32x4& Q1) {
    asm volatile(
        "global_load_dwordx4 %0, %4, off\n\t"
        "global_load_dwordx4 %1, %4, off offset:16\n\t"
        "global_load_dwordx4 %2, %5, off\n\t"
        "global_load_dwordx4 %3, %5, off offset:16"
        : "=&v"(P0), "=&v"(P1), "=&v"(Q0), "=&v"(Q1)
        : "v"(pa), "v"(ta)
        : "memory");
}

// rule #18: consumers are register-only ops that can hoist past an asm waitcnt;
// sched_barrier(0) immediately after is the fence.
#define VWAIT0() do { asm volatile("s_waitcnt vmcnt(0)" ::: "memory"); \
                      __builtin_amdgcn_sched_barrier(0); } while (0)

__global__ __launch_bounds__(NTHREADS, 4) void ghmc_pass1(
                           const float4* __restrict__ pred4,
                           const int4*   __restrict__ tgt4,
                           float*        __restrict__ gS,
                           unsigned int* __restrict__ gC,
                           unsigned int* __restrict__ gDone,
                           const float*  __restrict__ acc_sum,
                           float*        __restrict__ out,
                           int ngrp, int nit, int total, float tot) {
    __shared__ unsigned int sH[HWORDS];          // per-pair fused count|sum rows
    __shared__ unsigned int sPs[4 * BINS];       // per-wave partial sums (reduce)
    __shared__ unsigned int sPc[4 * BINS];       // per-wave partial counts
    __shared__ unsigned int sLast;
    const int t = threadIdx.x;

    for (int k = t; k < HWORDS; k += NTHREADS) sH[k] = 0u;
    __syncthreads();

    unsigned int* const row = &sH[(t >> 1) * RSTRIDE];

    const int stride = gridDim.x * blockDim.x;
    const int g0 = blockIdx.x * blockDim.x + t;      // g0 < stride <= ngrp: always valid
    const unsigned long long pb = (unsigned long long)pred4;
    const unsigned long long tb = (unsigned long long)tgt4;

    f32x4 pA0, pA1, pB0, pB1;
    i32x4 qA0, qA1, qB0, qB1;

    // prologue: group 0 into the A buffer
    issue4(pb + (unsigned long long)g0 * 32ull, tb + (unsigned long long)g0 * 32ull,
           pA0, pA1, qA0, qA1);

    // nit is even; out-of-range groups issue a clamped (g0) address and are
    // masked out of the ds_add by the per-lane g<ngrp check.
    for (int it = 0; it < nit; it += 2) {
        // ---- half A: group it ----
        VWAIT0();
        {   int gn = g0 + (it + 1) * stride;
            unsigned long long off = (unsigned long long)(gn < ngrp ? gn : g0) * 32ull;
            issue4(pb + off, tb + off, pB0, pB1, qB0, qB1);
        }
        {   int g = g0 + it * stride;
            if (g < ngrp) {
                #pragma unroll
                for (int j = 0; j < 4; ++j) ghm_elem(pA0[j], qA0[j], row);
                #pragma unroll
                for (int j = 0; j < 4; ++j) ghm_elem(pA1[j], qA1[j], row);
            }
        }
        // ---- half B: group it+1 ----
        VWAIT0();
        {   int gn = g0 + (it + 2) * stride;
            unsigned long long off = (unsigned long long)(gn < ngrp ? gn : g0) * 32ull;
            issue4(pb + off, tb + off, pA0, pA1, qA0, qA1);
        }
        {   int g = g0 + (it + 1) * stride;
            if (g < ngrp) {
                #pragma unroll
                for (int j = 0; j < 4; ++j) ghm_elem(pB0[j], qB0[j], row);
                #pragma unroll
                for (int j = 0; j < 4; ++j) ghm_elem(pB1[j], qB1[j], row);
            }
        }
    }
    // drain the final (unconsumed) prefetch before its regs can be reused
    asm volatile("s_waitcnt vmcnt(0)" ::: "memory");

    // tail (total % 8 != 0); N*C=32M divisible by 8 so normally dead code
    if (blockIdx.x == 0 && t == 0) {
        const float* predf = (const float*)pred4;
        const int*   tgtf  = (const int*)tgt4;
        for (int e = ngrp * 8; e < total; ++e) ghm_elem(predf[e], tgtf[e], row);
    }
    __syncthreads();

    // stage 1: each wave reduces 32 rows; lane l<30 handles bin l
    // bounds: count <= 32 * 256 = 8192; sum <= 32 * 2^20 = 2^25, fits u32
    {
        const int w = t >> 6;          // wave id 0..3
        const int l = t & 63;
        if (l < BINS) {
            unsigned int cs = 0u, ss = 0u;
            const int r0 = w * (NROWS / 4);   // 32 rows per wave
            #pragma unroll 8
            for (int r2 = 0; r2 < NROWS / 4; ++r2) {
                unsigned int v = sH[(r0 + r2) * RSTRIDE + l];
                cs += v >> 20;
                ss += v & SUM_MASK;
            }
            sPs[w * BINS + l] = ss;
            sPc[w * BINS + l] = cs;
        }
    }
    __syncthreads();

    // stage 2: threads 0..29 combine the 4 wave-partials, one global atomic each
    if (t < BINS) {
        unsigned int cs = 0u, ss = 0u;
        #pragma unroll
        for (int w = 0; w < 4; ++w) {
            ss += sPs[w * BINS + t];
            cs += sPc[w * BINS + t];
        }
        if (cs != 0u) {
            atomicAdd(&gS[t], (float)ss * INV_SSCALE);
            atomicAdd(&gC[t], cs);
        }
        __threadfence();               // order our atomics before the ticket
    }
    __syncthreads();

    // fused finalize: last block to arrive computes the loss (saves a launch).
    if (t == 0) sLast = (atomicAdd(gDone, 1u) == (unsigned int)(gridDim.x - 1)) ? 1u : 0u;
    __syncthreads();
    if (sLast && t < 64) {             // wave 0, all 64 lanes active
        unsigned int c = 0u; float s = 0.0f;
        if (t < BINS) {
            c = atomicAdd(&gC[t], 0u);          // atomic reads: coherent vs other XCDs
            s = atomicAdd(&gS[t], 0.0f);
        }
        unsigned long long m = __ballot(t < BINS && c != 0u);
        float nf = fmaxf((float)__popcll(m), 1.0f);
        float term = 0.0f;
        if (t < BINS && c != 0u) {
            float na = MMT * acc_sum[t] + (1.0f - MMT) * (float)c;
            term = (tot / na / nf) * s;
        }
        // all 64 lanes execute every __shfl; sequential b=0..29 order preserved
        float loss = 0.0f;
        for (int b = 0; b < BINS; ++b) loss += __shfl(term, b);
        if (t == 0) out[0] = (loss / tot) * LOSS_WEIGHT;
    }
}

extern "C" void kernel_launch(void* const* d_in, const int* in_sizes, int n_in,
                              void* d_out, int out_size, void* d_ws, size_t ws_size,
                              hipStream_t stream) {
    const float* pred    = (const float*)d_in[0];
    const int*   target  = (const int*)d_in[1];
    const float* acc_sum = (const float*)d_in[2];

    const int total = in_sizes[0];      // N*C = 32,000,000
    const int ngrp  = total / 8;        // 8 elems per thread-iteration

    float*        gS    = (float*)d_ws;
    unsigned int* gC    = (unsigned int*)((char*)d_ws + 256);
    unsigned int* gDone = (unsigned int*)((char*)d_ws + 512);

    hipMemsetAsync(d_ws, 0, 768, stream);

    const int blocks = 1024;            // 4 blocks/CU (16.9KB LDS), 16 waves/CU
    const int stride = blocks * NTHREADS;
    int nit = (ngrp + stride - 1) / stride;   // 16 for 32M elems
    nit = (nit + 1) & ~1;                     // even (A/B unroll)

    // max adds/row: 2 thr * nit(16) * 8 = 256 -> count fits bits[20..31];
    // fixed-point sum <= 256 * ~1540 ~= 394K < 2^20.
    ghmc_pass1<<<blocks, NTHREADS, 0, stream>>>(
        (const float4*)pred, (const int4*)target, gS, gC, gDone, acc_sum,
        (float*)d_out, ngrp, nit, total, (float)total);
}

// Round 5
// 314.544 us; speedup vs baseline: 1.0194x; 1.0194x over previous
//
#include <hip/hip_runtime.h>

#define BINS 30
#define MMT 0.75f
#define LOSS_WEIGHT 1.0f

#define RSTRIDE 31            // 30 bins + 1 pad; row r slot k -> bank (k-r)%32
#define NTHREADS 256
#define HWORDS (NTHREADS * RSTRIDE)   // 7936 words = 31744 B (epilogue only)
#define CNT_ONE (1u << 20)    // count in bits [20..31]; fixed-point sum in bits [0..19]
#define SUM_MASK 0xFFFFFu
#define SSCALE 256.0f
#define INV_SSCALE (1.0f / 256.0f)

// Workspace: float gS[64] @0, uint gC[64] @256, uint gDone @512 (zeroed each launch)

// Register prefix-accumulators: acc[k] accumulates (count|fixedsum) over elements
// with z >= T_k where T_k = logit(k/30). Per-bin b recovered by differencing in
// finalize (C_b = F_b - F_{b+1}). acc[0] is unconditional (F_0 = all elems).
// Hot loop is pure VALU + streaming loads: NO LDS scatter (r0-r4 ablations killed
// BW-bound, occupancy, MLP theories; the per-element 64-lane ds scatter is the
// last suspect for the ~70-110us stall on top of the constant ~30us VALU time).
__device__ __forceinline__ void ghm_elem(float x, int tt, unsigned int (&acc)[BINS]) {
    // T_k = ln(k/(30-k)), k=1..29 (index 0 unused)
    constexpr float TK[BINS] = {
        0.0f,
        -3.3672958f, -2.6390573f, -2.1972246f, -1.8718022f, -1.6094379f,
        -1.3862944f, -1.1895841f, -1.0116009f, -0.84729786f, -0.69314718f,
        -0.54654371f, -0.40546511f, -0.26826399f, -0.13353139f, 0.0f,
         0.13353139f, 0.26826399f, 0.40546511f, 0.54654371f, 0.69314718f,
         0.84729786f, 1.0116009f, 1.1895841f, 1.3862944f, 1.6094379f,
         1.8718022f, 2.1972246f, 2.6390573f, 3.3672958f };
    // z = (1-2t)x via sign-bit xor; g = sigmoid(z); bce = softplus(z)
    float z  = __uint_as_float(__float_as_uint(x) ^ ((unsigned int)tt << 31));
    float e  = __expf(-fabsf(z));              // v_mul + v_exp
    float h  = 1.0f + e;
    float sp = fmaxf(z, 0.0f) + __logf(h);     // softplus(z) >= 0
    unsigned int v = (unsigned int)(sp * SSCALE + 0.5f) + CNT_ONE;
    acc[0] += v;
    #pragma unroll
    for (int k = 1; k < BINS; ++k)             // static idx: stays in registers
        acc[k] += (z >= TK[k]) ? v : 0u;
}

__global__ __launch_bounds__(NTHREADS, 4) void ghmc_pass1(
                           const float4* __restrict__ pred4,
                           const int4*   __restrict__ tgt4,
                           float*        __restrict__ gS,
                           unsigned int* __restrict__ gC,
                           unsigned int* __restrict__ gDone,
                           const float*  __restrict__ acc_sum,
                           float*        __restrict__ out,
                           int nvec, int total, float tot) {
    __shared__ unsigned int sH[HWORDS];          // written ONCE in epilogue
    __shared__ unsigned int sPs[4 * BINS];       // per-wave partial sums
    __shared__ unsigned int sPc[4 * BINS];       // per-wave partial counts
    __shared__ unsigned int sLast;
    const int t = threadIdx.x;

    unsigned int acc[BINS];
    #pragma unroll
    for (int k = 0; k < BINS; ++k) acc[k] = 0u;

    // plain grid-stride streaming; per-group compute (~790 cyc) hides latency
    const int stride = gridDim.x * blockDim.x;
    for (int i = blockIdx.x * blockDim.x + t; i < nvec; i += stride) {
        float4 p  = pred4[i];
        int4   tv = tgt4[i];
        ghm_elem(p.x, tv.x, acc);
        ghm_elem(p.y, tv.y, acc);
        ghm_elem(p.z, tv.z, acc);
        ghm_elem(p.w, tv.w, acc);
    }

    // tail (nvec*4 < total); N*C=32M divisible by 4 so normally dead code
    if (blockIdx.x == 0 && t == 0) {
        const float* predf = (const float*)pred4;
        const int*   tgtf  = (const int*)tgt4;
        for (int e = nvec * 4; e < total; ++e) ghm_elem(predf[e], tgtf[e], acc);
    }

    // epilogue: dump packed accs to padded LDS (one conflict-light pass), then
    // r0's verified stage-1/2 reduction on prefix values.
    {
        unsigned int* rowp = &sH[t * RSTRIDE];
        #pragma unroll
        for (int k = 0; k < BINS; ++k) rowp[k] = acc[k];
    }
    __syncthreads();

    // stage 1: each wave reduces 64 rows; lane l<30 handles prefix-slot l
    // bounds: count <= 64*127 = 8128; sum <= 64*192K ~= 12.3M, fits u32
    {
        const int w = t >> 6;          // wave id 0..3
        const int l = t & 63;
        if (l < BINS) {
            unsigned int cs = 0u, ss = 0u;
            const int r0 = w * 64;
            #pragma unroll 8
            for (int r2 = 0; r2 < 64; ++r2) {
                unsigned int v = sH[(r0 + r2) * RSTRIDE + l];
                cs += v >> 20;
                ss += v & SUM_MASK;
            }
            sPs[w * BINS + l] = ss;
            sPc[w * BINS + l] = cs;
        }
    }
    __syncthreads();

    // stage 2: threads 0..29 combine the 4 wave-partials, one global atomic each.
    // gC[k]/gS[k] hold PREFIX totals F_k / G_k (k=0 unconditional).
    if (t < BINS) {
        unsigned int cs = 0u, ss = 0u;
        #pragma unroll
        for (int w = 0; w < 4; ++w) {
            ss += sPs[w * BINS + t];
            cs += sPc[w * BINS + t];
        }
        if (cs != 0u) {
            atomicAdd(&gS[t], (float)ss * INV_SSCALE);
            atomicAdd(&gC[t], cs);
        }
        __threadfence();               // order our atomics before the ticket
    }
    __syncthreads();

    // fused finalize: last block computes loss from prefix differences.
    if (t == 0) sLast = (atomicAdd(gDone, 1u) == (unsigned int)(gridDim.x - 1)) ? 1u : 0u;
    __syncthreads();
    if (sLast && t < 64) {             // wave 0, all 64 lanes active
        unsigned int f = 0u; float gsum = 0.0f;
        if (t < BINS) {
            f    = atomicAdd(&gC[t], 0u);       // F_t (prefix count)
            gsum = atomicAdd(&gS[t], 0.0f);     // G_t (prefix sum)
        }
        // per-bin via difference with next prefix (bin 29: F_30 = 0)
        unsigned int fn = __shfl(f, (t + 1) & 63);
        float        gn = __shfl(gsum, (t + 1) & 63);
        unsigned int c  = 0u; float s = 0.0f;
        if (t < BINS) {
            c = (t == BINS - 1) ? f : f - fn;
            s = (t == BINS - 1) ? gsum : gsum - gn;
        }
        unsigned long long m = __ballot(t < BINS && c != 0u);
        float nf = fmaxf((float)__popcll(m), 1.0f);
        float term = 0.0f;
        if (t < BINS && c != 0u) {
            float na = MMT * acc_sum[t] + (1.0f - MMT) * (float)c;
            term = (tot / na / nf) * s;
        }
        // all 64 lanes execute every __shfl; sequential b=0..29 order preserved
        float loss = 0.0f;
        for (int b = 0; b < BINS; ++b) loss += __shfl(term, b);
        if (t == 0) out[0] = (loss / tot) * LOSS_WEIGHT;
    }
}

extern "C" void kernel_launch(void* const* d_in, const int* in_sizes, int n_in,
                              void* d_out, int out_size, void* d_ws, size_t ws_size,
                              hipStream_t stream) {
    const float* pred    = (const float*)d_in[0];
    const int*   target  = (const int*)d_in[1];
    const float* acc_sum = (const float*)d_in[2];

    const int total = in_sizes[0];      // N*C = 32,000,000
    const int nvec  = total / 4;

    float*        gS    = (float*)d_ws;
    unsigned int* gC    = (unsigned int*)((char*)d_ws + 256);
    unsigned int* gDone = (unsigned int*)((char*)d_ws + 512);

    hipMemsetAsync(d_ws, 0, 768, stream);

    // 1024 blocks, 32.8KB LDS -> 4 blocks/CU, 16 waves/CU.
    // per-thread adds <= 31 iters * 4 + tail(3) = 127 -> count fits 12-bit field;
    // fixed-point sum <= 127 * ~1510 ~= 192K < 2^20.
    const int blocks = 1024;
    ghmc_pass1<<<blocks, NTHREADS, 0, stream>>>(
        (const float4*)pred, (const int4*)target, gS, gC, gDone, acc_sum,
        (float*)d_out, nvec, total, (float)total);
}